// Round 10
// baseline (410.830 us; speedup 1.0000x reference)
//
#include <hip/hip_runtime.h>
#include <hip/hip_bf16.h>

typedef __attribute__((ext_vector_type(8))) short bfrag;   // 8 x bf16 (4 VGPRs)
typedef __attribute__((ext_vector_type(4))) short bhalf4;  // 4 x bf16
typedef __attribute__((ext_vector_type(4))) float ffrag;   // 4 x f32 acc

#define NB 1024
#define NT 256

static __device__ __forceinline__ float fast_rcp(float x) { return __builtin_amdgcn_rcpf(x); }
static __device__ __forceinline__ float sigm(float x) {
  return fast_rcp(1.f + __builtin_amdgcn_exp2f(-1.44269504f * x));
}
static __device__ __forceinline__ float tanh_f(float x) {
  return __builtin_fmaf(2.f, fast_rcp(1.f + __builtin_amdgcn_exp2f(-2.88539008f * x)), -1.f);
}
static __device__ __forceinline__ float bf2f(__hip_bfloat16 v) { return __bfloat162float(v); }
static __device__ __forceinline__ short f2bs(float f) {
  __hip_bfloat16 h = __float2bfloat16(f);
  return *reinterpret_cast<short*>(&h);
}
// LDS-only barrier: skip the vmcnt(0) drain __syncthreads would force.
static __device__ __forceinline__ void barrier_lgkm() {
  asm volatile("s_waitcnt lgkmcnt(0)\n\ts_barrier" ::: "memory");
}

// ---------------------------------------------------------------------------
// Persistent GRU: 64 blocks x 16 rows, 512 threads (8 waves, 2/SIMD).
// R10 = R8 structure (chunk load + LDS write in the SAME step: no registers
// live across the barrier, no spill) + y race fixed by TRIPLE-buffered y_chb:
// write chunk c+1 -> buf (c+1)%3 at step 16c; S2 reads chunk (t-1)>>4 from
// buf ((t-1)>>4)%3 — write/read buffers differ by 2 mod 3 at the racy step.
// Rest: t-loop unroll x2, per-wave kc rotation, K-split gx + reg-seeded accs,
// wave-7 logit MFMA, one lgkm-only barrier/step, 16-step chunked eps/y.
// ---------------------------------------------------------------------------
__global__ __launch_bounds__(512, 2) void gru_kernel(
    const float* __restrict__ x,     // [B,64]
    const int* __restrict__ a_ids,   // [B,T]
    const int* __restrict__ t_ids,   // [B,T]
    const float* __restrict__ y,     // [B,T]
    const float* __restrict__ eps,   // [B,T,16]
    const float* __restrict__ Wx,    // [64,64]
    const float* __restrict__ bx,    // [64]
    const float* __restrict__ Ea,    // [100,32]
    const float* __restrict__ Et,    // [4,16]
    const float* __restrict__ Wih,   // [384,129]
    const float* __restrict__ Whh,   // [384,128]
    const float* __restrict__ bih,   // [384]
    const float* __restrict__ bhh,   // [384]
    const float* __restrict__ W0,    // [128,80]
    const float* __restrict__ b0g,   // [128]
    const float* __restrict__ Wy,    // [1,128]
    const float* __restrict__ by,    // [1]
    float* __restrict__ out)         // [B,T,2]
{
  // ---- persistent LDS ----
  __shared__ __align__(16) __hip_bfloat16 h_bf[2][16][136];  // h mirror (h_bf[1] = xdyn in prologue)
  __shared__ __align__(16) __hip_bfloat16 ind_s[2][16][72];  // dyn input [aenc|tenc|eps]
  __shared__ __align__(16) __hip_bfloat16 Ea_s[100][32];
  __shared__ __align__(16) __hip_bfloat16 Et_s[4][16];
  __shared__ float bsum_r[128], bsum_z[128], bihn_s[128], bhhn_s[128];
  __shared__ float wprev_s[384];
  // ---- unioned region (38912 B) ----
  // persistent: aid[16][256]u16 @0 | tix[16][256]u16 @8192 | eps_ch[2][16][16][16]bf16 @16384
  //             y_chb[3][16][16]bf16 @32768 (1536 B) | out_b[32][16][2]f32 @34816
  // prologue:   Wxb[64][64]bf16 @0 | W0b[128][80]bf16 @8192 | x_s[16][65]f32 @28672
  //             eps0s[16][17]f32 @32832 | xe_s[16][65]f32 @33920 | h0f[16][128]f32 @0
  //             (prologue aliases of 32768..34304 are dead before y_chb is written)
  __shared__ __align__(16) char uni[38912];
  unsigned short* aid_s   = (unsigned short*)(uni);
  unsigned short* tix_s   = (unsigned short*)(uni + 8192);
  __hip_bfloat16* eps_ch  = (__hip_bfloat16*)(uni + 16384);
  __hip_bfloat16* y_chb   = (__hip_bfloat16*)(uni + 32768);
  float*          out_b   = (float*)(uni + 34816);
  __hip_bfloat16* Wxb     = (__hip_bfloat16*)(uni);
  __hip_bfloat16* W0b     = (__hip_bfloat16*)(uni + 8192);
  float*          x_s     = (float*)(uni + 28672);
  float*          eps0s   = (float*)(uni + 32832);
  float*          xe_s    = (float*)(uni + 33920);
  float*          h0f     = (float*)(uni);

  const int tid = threadIdx.x;
  const int w = tid >> 6, l = tid & 63;
  const int lmod = l & 15, ldiv = l >> 4;
  const int i_own = 16 * w + lmod;
  const int b0 = blockIdx.x * 16;

  // ================= PROLOGUE =================
  if (tid < 128) {
    bsum_r[tid] = bih[tid] + bhh[tid];
    bsum_z[tid] = bih[128 + tid] + bhh[128 + tid];
    bihn_s[tid] = bih[256 + tid];
    bhhn_s[tid] = bhh[256 + tid];
  }
  if (tid < 384) wprev_s[tid] = Wih[tid * 129 + 128];
  for (int j = tid; j < 3200; j += 512) ((__hip_bfloat16*)Ea_s)[j] = __float2bfloat16(Ea[j]);
  if (tid < 64) ((__hip_bfloat16*)Et_s)[tid] = __float2bfloat16(Et[tid]);
  for (int j = tid; j < 4096; j += 512)  Wxb[j] = __float2bfloat16(Wx[j]);
  for (int j = tid; j < 10240; j += 512) W0b[j] = __float2bfloat16(W0[j]);
  for (int j = tid; j < 1024; j += 512) {
    int r = j >> 6, c = j & 63;
    x_s[r * 65 + c] = x[(b0 + r) * 64 + c];
  }
  if (tid < 256) {
    int r = tid >> 4, c = tid & 15;
    eps0s[r * 17 + c] = eps[((b0 + r) * NT) * 16 + c];
  }
  const float by_f = by[0];

  // persistent B-frags: wave w owns gate-cols i_own of r/z/n.
  bfrag Bh[3][4], Bi[3][2];
  #pragma unroll
  for (int g = 0; g < 3; g++) {
    int n = (g * 8 + w) * 16 + lmod;
    #pragma unroll
    for (int kc = 0; kc < 4; kc++) {
      int k = kc * 32 + ldiv * 8;
      const float* wh = Whh + n * 128 + k;
      float4 h0v = *reinterpret_cast<const float4*>(wh);
      float4 h1v = *reinterpret_cast<const float4*>(wh + 4);
      bfrag th = {f2bs(h0v.x), f2bs(h0v.y), f2bs(h0v.z), f2bs(h0v.w),
                  f2bs(h1v.x), f2bs(h1v.y), f2bs(h1v.z), f2bs(h1v.w)};
      Bh[g][kc] = th;
    }
    #pragma unroll
    for (int kc = 0; kc < 2; kc++) {
      bfrag ti;
      #pragma unroll
      for (int j = 0; j < 8; j++) {
        int dk = kc * 32 + ldiv * 8 + j;
        int col = dk < 48 ? dk : dk + 64;
        ti[j] = f2bs(Wih[n * 129 + col]);
      }
      Bi[g][kc] = ti;
    }
  }
  // logit B-tile for wave 7: col 0 = Wy, other cols 0
  bfrag Bl[4];
  if (w == 7) {
    #pragma unroll
    for (int kc = 0; kc < 4; kc++) {
      bfrag bt;
      #pragma unroll
      for (int j = 0; j < 8; j++)
        bt[j] = (lmod == 0) ? f2bs(Wy[kc * 32 + ldiv * 8 + j]) : (short)0;
      Bl[kc] = bt;
    }
  }
  __syncthreads();  // x_s, Wxb, tables ready

  // ph1: xenc = x@Wx.T + bx -> xe_s (f32) + xdyn bf16 (in h_bf[1])
  for (int j = tid; j < 1024; j += 512) {
    int r = j & 15, i = j >> 4;
    float acc = bx[i];
    #pragma unroll 8
    for (int k = 0; k < 64; k++) acc += x_s[r * 65 + k] * bf2f(Wxb[i * 64 + k]);
    xe_s[r * 65 + i] = acc;
    h_bf[1][r][i] = __float2bfloat16(acc);
  }
  __syncthreads();  // xe_s + xdyn ready; Wxb dead

  // ph2: h0 = tanh([xenc,eps0]@W0.T + b0) -> h0f (overwrites Wxb region)
  for (int j = tid; j < 2048; j += 512) {
    int r = j & 15, o = j >> 4;
    float acc = b0g[o];
    #pragma unroll 8
    for (int k = 0; k < 64; k++) acc += xe_s[r * 65 + k] * bf2f(W0b[o * 80 + k]);
    #pragma unroll
    for (int k = 0; k < 16; k++) acc += eps0s[r * 17 + k] * bf2f(W0b[o * 80 + 64 + k]);
    h0f[r * 128 + o] = tanh_f(acc);
  }

  // gxc = xenc @ Wih[:,48:112].T + per-gate biases folded into the seed
  ffrag gxc[3];
  {
    ffrag z = {0.f, 0.f, 0.f, 0.f};
    gxc[0] = z; gxc[1] = z; gxc[2] = z;
    #pragma unroll
    for (int kc = 0; kc < 2; kc++) {
      bfrag axd = *reinterpret_cast<const bfrag*>(&h_bf[1][lmod][kc * 32 + ldiv * 8]);
      #pragma unroll
      for (int g = 0; g < 3; g++) {
        int n = (g * 8 + w) * 16 + lmod;
        const float* wi = Wih + n * 129 + 48 + kc * 32 + ldiv * 8;
        bfrag bt;
        #pragma unroll
        for (int j = 0; j < 8; j++) bt[j] = f2bs(wi[j]);
        gxc[g] = __builtin_amdgcn_mfma_f32_16x16x32_bf16(axd, bt, gxc[g], 0, 0, 0);
      }
    }
    float brf = bsum_r[i_own], bzf = bsum_z[i_own], bn1 = bihn_s[i_own];
    #pragma unroll
    for (int q = 0; q < 4; q++) {
      gxc[0][q] += brf;
      gxc[1][q] += bzf;
      gxc[2][q] += bn1;
    }
  }
  __syncthreads();  // h0f complete; gxc done

  // h init: fp32 regs + bf16 mirror in h_bf[0]
  float h_reg[4];
  #pragma unroll
  for (int q = 0; q < 4; q++) {
    int row = ldiv * 4 + q;
    float hv = h0f[row * 128 + i_own];
    h_reg[q] = hv;
    h_bf[0][row][i_own] = __float2bfloat16(hv);
  }
  __syncthreads();  // h0f dead; uni becomes persistent

  // ids + chunk 0 of eps/y (y chunk 0 -> buffer 0)
  for (int j = tid; j < 4096; j += 512) {
    int r = j >> 8, t = j & 255;
    aid_s[r * 256 + t] = (unsigned short)a_ids[(b0 + r) * NT + t];
    tix_s[r * 256 + t] = (unsigned short)t_ids[(b0 + r) * NT + t];
  }
  {
    int r = tid >> 5, sub = tid & 31;
    const float* p = eps + ((b0 + r) * NT + 0) * 16 + sub * 8;
    float4 eA0 = *reinterpret_cast<const float4*>(p);
    float4 eB0 = *reinterpret_cast<const float4*>(p + 4);
    int toff = sub >> 1, c8 = (sub & 1) * 8;
    bfrag e = {f2bs(eA0.x), f2bs(eA0.y), f2bs(eA0.z), f2bs(eA0.w),
               f2bs(eB0.x), f2bs(eB0.y), f2bs(eB0.z), f2bs(eB0.w)};
    *reinterpret_cast<bfrag*>(&eps_ch[(toff * 16 + r) * 16 + c8]) = e;
    if (tid < 64) {
      int r2 = tid >> 2, s2 = tid & 3;
      float4 yv0 = *reinterpret_cast<const float4*>(y + (b0 + r2) * NT + s2 * 4);
      bhalf4 yb = {f2bs(yv0.x), f2bs(yv0.y), f2bs(yv0.z), f2bs(yv0.w)};
      *reinterpret_cast<bhalf4*>(&y_chb[r2 * 16 + s2 * 4]) = yb;
    }
  }
  __syncthreads();

  // stage dyn input for t=0: 128 threads (waves 4-5) emb+eps
  const bool do_emb = (tid >= 256 && tid < 384);
  const int er8 = (tid - 256) >> 3, ch = (tid - 256) & 7;
  if (do_emb) {
    int j = tid - 256, r = j >> 3, c = j & 7;
    bfrag e;
    if (c < 4)      e = *reinterpret_cast<const bfrag*>(&Ea_s[aid_s[r * 256]][c * 8]);
    else if (c < 6) e = *reinterpret_cast<const bfrag*>(&Et_s[tix_s[r * 256]][(c - 4) * 8]);
    else            e = *reinterpret_cast<const bfrag*>(&eps_ch[(r) * 16 + (c - 6) * 8]);
    *reinterpret_cast<bfrag*>(&ind_s[0][r][c * 8]) = e;
  }
  // hoisted per-lane constants
  const float wpr = wprev_s[i_own], wpz = wprev_s[128 + i_own], wpn = wprev_s[256 + i_own];
  const float bn2 = bhhn_s[i_own];
  __syncthreads();

  // ================= MAIN LOOP (unrolled x2: buf const per copy) ===========
  #pragma unroll 2
  for (int t = 0; t < NT; t++) {
    const int buf = t & 1, nbuf = buf ^ 1;

    // flush completed chunk (rare; waves 0-1)
    if ((t & 15) == 1 && t > 16 && tid < 128) {
      int fc = (t - 17) >> 4;
      int r = tid >> 3, k = tid & 7;
      int s = fc * 16 + 2 * k, slot = s & 31;
      float4 v;
      v.x = out_b[slot * 32 + r * 2];
      v.y = out_b[slot * 32 + r * 2 + 1];
      v.z = out_b[(slot + 1) * 32 + r * 2];
      v.w = out_b[(slot + 1) * 32 + r * 2 + 1];
      *reinterpret_cast<float4*>(out + ((b0 + r) * NT + s) * 2) = v;
    }

    // issue next-chunk global loads (rare; written to LDS at this step's
    // bottom — same iteration, no cross-barrier register liveness)
    const bool ck = ((t & 15) == 0) && (t + 16 < NT);
    float4 eA, eB, yv;
    const int cr = tid >> 5, csub = tid & 31;
    if (ck) {
      const float* p = eps + ((b0 + cr) * NT + t + 16) * 16 + csub * 8;
      eA = *reinterpret_cast<const float4*>(p);
      eB = *reinterpret_cast<const float4*>(p + 4);
      if (tid < 64) {
        int r2 = tid >> 2, s2 = tid & 3;
        yv = *reinterpret_cast<const float4*>(y + (b0 + r2) * NT + t + 16 + s2 * 4);
      }
    }

    // stage step t+1 dyn input (waves 4-5)
    const int t1 = (t + 1 < NT) ? t + 1 : NT - 1;
    if (do_emb) {
      bfrag e;
      if (ch < 4)      e = *reinterpret_cast<const bfrag*>(&Ea_s[aid_s[er8 * 256 + t1]][ch * 8]);
      else if (ch < 6) e = *reinterpret_cast<const bfrag*>(&Et_s[tix_s[er8 * 256 + t1]][(ch - 4) * 8]);
      else             e = *reinterpret_cast<const bfrag*>(
                           &eps_ch[((((t1 >> 4) & 1) * 16 + (t1 & 15)) * 16 + er8) * 16 + (ch - 6) * 8]);
      *reinterpret_cast<bfrag*>(&ind_s[nbuf][er8][ch * 8]) = e;
    }

    // MFMA: merged accumulators, per-wave kc rotation
    ffrag ar = gxc[0], az = gxc[1], anx = gxc[2], anh, agl;
    #pragma unroll
    for (int q = 0; q < 4; q++) anh[q] = bn2;
    #pragma unroll
    for (int i = 0; i < 2; i++) {
      int kc = (i + w) & 1;
      bfrag ax = *reinterpret_cast<const bfrag*>(&ind_s[buf][lmod][kc * 32 + ldiv * 8]);
      ar  = __builtin_amdgcn_mfma_f32_16x16x32_bf16(ax, Bi[0][kc], ar, 0, 0, 0);
      az  = __builtin_amdgcn_mfma_f32_16x16x32_bf16(ax, Bi[1][kc], az, 0, 0, 0);
      anx = __builtin_amdgcn_mfma_f32_16x16x32_bf16(ax, Bi[2][kc], anx, 0, 0, 0);
    }
    if (w == 7) {
      #pragma unroll
      for (int q = 0; q < 4; q++) agl[q] = by_f;
    }
    #pragma unroll
    for (int i = 0; i < 4; i++) {
      int kc = (i + w) & 3;
      bfrag ah = *reinterpret_cast<const bfrag*>(&h_bf[buf][lmod][kc * 32 + ldiv * 8]);
      ar  = __builtin_amdgcn_mfma_f32_16x16x32_bf16(ah, Bh[0][kc], ar, 0, 0, 0);
      az  = __builtin_amdgcn_mfma_f32_16x16x32_bf16(ah, Bh[1][kc], az, 0, 0, 0);
      anh = __builtin_amdgcn_mfma_f32_16x16x32_bf16(ah, Bh[2][kc], anh, 0, 0, 0);
      if (w == 7)
        agl = __builtin_amdgcn_mfma_f32_16x16x32_bf16(ah, Bl[kc], agl, 0, 0, 0);
    }

    // wave 7: logit/prob for step t-1
    if (w == 7 && t > 0 && lmod == 0) {
      int slot = (t - 1) & 31;
      #pragma unroll
      for (int q = 0; q < 4; q++) {
        int row = ldiv * 4 + q;
        float lg = agl[q];
        out_b[slot * 32 + row * 2]     = lg;
        out_b[slot * 32 + row * 2 + 1] = sigm(lg);
      }
    }

    // S2: gates, h update. py from TRIPLE-buffered y chunk: read buffer
    // ((t-1)>>4)%3 can never equal the buffer written this step ((t>>4)+1)%3.
    {
      const int tm1 = (t > 0) ? t - 1 : 0;
      const int rb = (tm1 >> 4) % 3;
      #pragma unroll
      for (int q = 0; q < 4; q++) {
        int row = ldiv * 4 + q;
        float py = (t == 0) ? 0.f
                 : bf2f(y_chb[rb * 256 + row * 16 + (tm1 & 15)]);
        float rv = sigm(__builtin_fmaf(py, wpr, ar[q]));
        float zv = sigm(__builtin_fmaf(py, wpz, az[q]));
        float nv = tanh_f(__builtin_fmaf(py, wpn, anx[q]) + rv * anh[q]);
        float hn = __builtin_fmaf(zv, h_reg[q] - nv, nv);
        h_reg[q] = hn;
        h_bf[nbuf][row][i_own] = __float2bfloat16(hn);
      }
    }

    // next-chunk convert + LDS write (same step as load; y -> buf (c+1)%3)
    if (ck) {
      int cbe = ((t >> 4) + 1) & 1;
      int cby = ((t >> 4) + 1) % 3;
      int toff = csub >> 1, c8 = (csub & 1) * 8;
      bfrag e = {f2bs(eA.x), f2bs(eA.y), f2bs(eA.z), f2bs(eA.w),
                 f2bs(eB.x), f2bs(eB.y), f2bs(eB.z), f2bs(eB.w)};
      *reinterpret_cast<bfrag*>(&eps_ch[((cbe * 16 + toff) * 16 + cr) * 16 + c8]) = e;
      if (tid < 64) {
        int r2 = tid >> 2, s2 = tid & 3;
        bhalf4 yb = {f2bs(yv.x), f2bs(yv.y), f2bs(yv.z), f2bs(yv.w)};
        *reinterpret_cast<bhalf4*>(&y_chb[cby * 256 + r2 * 16 + s2 * 4]) = yb;
      }
    }

    barrier_lgkm();  // the ONE barrier per step (LDS-only drain)
  }

  // ---- tail: logit for step 255 from h_bf[0] (= H_256), then flush ----
  if (w == 7) {
    ffrag agl;
    #pragma unroll
    for (int q = 0; q < 4; q++) agl[q] = by_f;
    #pragma unroll
    for (int kc = 0; kc < 4; kc++) {
      bfrag ah = *reinterpret_cast<const bfrag*>(&h_bf[0][lmod][kc * 32 + ldiv * 8]);
      agl = __builtin_amdgcn_mfma_f32_16x16x32_bf16(ah, Bl[kc], agl, 0, 0, 0);
    }
    if (lmod == 0) {
      #pragma unroll
      for (int q = 0; q < 4; q++) {
        int row = ldiv * 4 + q;
        float lg = agl[q];
        out_b[31 * 32 + row * 2]     = lg;
        out_b[31 * 32 + row * 2 + 1] = sigm(lg);
      }
    }
  }
  __syncthreads();
  if (tid < 128) {
    int r = tid >> 3, k = tid & 7;
    int s = 240 + 2 * k, slot = s & 31;
    float4 v;
    v.x = out_b[slot * 32 + r * 2];
    v.y = out_b[slot * 32 + r * 2 + 1];
    v.z = out_b[(slot + 1) * 32 + r * 2];
    v.w = out_b[(slot + 1) * 32 + r * 2 + 1];
    *reinterpret_cast<float4*>(out + ((b0 + r) * NT + s) * 2) = v;
  }
}

extern "C" void kernel_launch(void* const* d_in, const int* in_sizes, int n_in,
                              void* d_out, int out_size, void* d_ws, size_t ws_size,
                              hipStream_t stream) {
  const float* x   = (const float*)d_in[0];
  const int*   a   = (const int*)d_in[1];
  const int*   tt  = (const int*)d_in[2];
  const float* y   = (const float*)d_in[3];
  // d_in[4] = mask: forward output is mask-independent (m*v + (1-m)*v == v)
  const float* eps = (const float*)d_in[5];
  const float* Wx  = (const float*)d_in[6];
  const float* bx  = (const float*)d_in[7];
  const float* Ea  = (const float*)d_in[8];
  const float* Et  = (const float*)d_in[9];
  const float* Wih = (const float*)d_in[10];
  const float* Whh = (const float*)d_in[11];
  const float* bih = (const float*)d_in[12];
  const float* bhh = (const float*)d_in[13];
  const float* W0  = (const float*)d_in[14];
  const float* b0  = (const float*)d_in[15];
  const float* Wy  = (const float*)d_in[16];
  const float* by  = (const float*)d_in[17];
  float* out = (float*)d_out;

  gru_kernel<<<NB / 16, 512, 0, stream>>>(x, a, tt, y, eps, Wx, bx, Ea, Et,
                                          Wih, Whh, bih, bhh, W0, b0, Wy, by, out);
}

// Round 11
// 366.214 us; speedup vs baseline: 1.1218x; 1.1218x over previous
//
#include <hip/hip_runtime.h>
#include <hip/hip_bf16.h>

typedef __attribute__((ext_vector_type(8))) short bfrag;   // 8 x bf16 (4 VGPRs)
typedef __attribute__((ext_vector_type(4))) float ffrag;   // 4 x f32 acc

#define NB 1024
#define NT 256

static __device__ __forceinline__ float fast_rcp(float x) { return __builtin_amdgcn_rcpf(x); }
static __device__ __forceinline__ float sigm(float x) {
  return fast_rcp(1.f + __builtin_amdgcn_exp2f(-1.44269504f * x));
}
static __device__ __forceinline__ float tanh_f(float x) {
  return __builtin_fmaf(2.f, fast_rcp(1.f + __builtin_amdgcn_exp2f(-2.88539008f * x)), -1.f);
}
static __device__ __forceinline__ float bf2f(__hip_bfloat16 v) { return __bfloat162float(v); }
static __device__ __forceinline__ short f2bs(float f) {
  __hip_bfloat16 h = __float2bfloat16(f);
  return *reinterpret_cast<short*>(&h);
}
// LDS-only barrier: skip the vmcnt(0) drain __syncthreads would force.
static __device__ __forceinline__ void barrier_lgkm() {
  asm volatile("s_waitcnt lgkmcnt(0)\n\ts_barrier" ::: "memory");
}

// ---------------------------------------------------------------------------
// Persistent GRU: 64 blocks x 16 rows, 512 threads (8 waves, 2/SIMD).
// R11 = exact R7 structure (known-good: no unroll-2 / no kc rotation — those
// caused scratch spills, WRITE_SIZE 2048->8192 KB in R9/R10) + ONE change:
// Ea_s rows padded 32->40 elements (80 B, 16B-aligned) so random-row gathers
// spread over 8 bank groups (aid*20%32) instead of 2 (aid*16%32).
// ---------------------------------------------------------------------------
__global__ __launch_bounds__(512, 2) void gru_kernel(
    const float* __restrict__ x,     // [B,64]
    const int* __restrict__ a_ids,   // [B,T]
    const int* __restrict__ t_ids,   // [B,T]
    const float* __restrict__ y,     // [B,T]
    const float* __restrict__ eps,   // [B,T,16]
    const float* __restrict__ Wx,    // [64,64]
    const float* __restrict__ bx,    // [64]
    const float* __restrict__ Ea,    // [100,32]
    const float* __restrict__ Et,    // [4,16]
    const float* __restrict__ Wih,   // [384,129]
    const float* __restrict__ Whh,   // [384,128]
    const float* __restrict__ bih,   // [384]
    const float* __restrict__ bhh,   // [384]
    const float* __restrict__ W0,    // [128,80]
    const float* __restrict__ b0g,   // [128]
    const float* __restrict__ Wy,    // [1,128]
    const float* __restrict__ by,    // [1]
    float* __restrict__ out)         // [B,T,2]
{
  // ---- persistent LDS ----
  __shared__ __align__(16) __hip_bfloat16 h_bf[2][16][136];  // h mirror (h_bf[1] = xdyn in prologue)
  __shared__ __align__(16) __hip_bfloat16 ind_s[2][16][72];  // dyn input [aenc|tenc|eps]
  __shared__ __align__(16) __hip_bfloat16 Ea_s[100][40];     // PADDED rows (data in cols 0..31)
  __shared__ __align__(16) __hip_bfloat16 Et_s[4][16];
  __shared__ float prevy_s[2][16];
  __shared__ float bsum_r[128], bsum_z[128], bihn_s[128], bhhn_s[128];
  __shared__ float wprev_s[384];
  // ---- unioned region (38912 B) ----
  // persistent: aid[16][256]u16 @0 | tix[16][256]u16 @8192 | eps_ch[2][16][16][16]bf16 @16384
  //             y_ch[2][16][16]f32 @32768 | out_b[32][16][2]f32 @34816
  // prologue:   Wxb[64][64]bf16 @0 | W0b[128][80]bf16 @8192 | x_s[16][65]f32 @28672
  //             eps0s[16][17]f32 @32832 | xe_s[16][65]f32 @33920 | h0f[16][128]f32 @0
  __shared__ __align__(16) char uni[38912];
  unsigned short* aid_s   = (unsigned short*)(uni);
  unsigned short* tix_s   = (unsigned short*)(uni + 8192);
  __hip_bfloat16* eps_ch  = (__hip_bfloat16*)(uni + 16384);
  float*          y_ch    = (float*)(uni + 32768);
  float*          out_b   = (float*)(uni + 34816);
  __hip_bfloat16* Wxb     = (__hip_bfloat16*)(uni);
  __hip_bfloat16* W0b     = (__hip_bfloat16*)(uni + 8192);
  float*          x_s     = (float*)(uni + 28672);
  float*          eps0s   = (float*)(uni + 32832);
  float*          xe_s    = (float*)(uni + 33920);
  float*          h0f     = (float*)(uni);

  const int tid = threadIdx.x;
  const int w = tid >> 6, l = tid & 63;
  const int lmod = l & 15, ldiv = l >> 4;
  const int i_own = 16 * w + lmod;
  const int b0 = blockIdx.x * 16;

  // ================= PROLOGUE =================
  if (tid < 128) {
    bsum_r[tid] = bih[tid] + bhh[tid];
    bsum_z[tid] = bih[128 + tid] + bhh[128 + tid];
    bihn_s[tid] = bih[256 + tid];
    bhhn_s[tid] = bhh[256 + tid];
  }
  if (tid < 384) wprev_s[tid] = Wih[tid * 129 + 128];
  for (int j = tid; j < 3200; j += 512) {
    int r = j >> 5, c = j & 31;
    Ea_s[r][c] = __float2bfloat16(Ea[j]);
  }
  if (tid < 64) ((__hip_bfloat16*)Et_s)[tid] = __float2bfloat16(Et[tid]);
  for (int j = tid; j < 4096; j += 512)  Wxb[j] = __float2bfloat16(Wx[j]);
  for (int j = tid; j < 10240; j += 512) W0b[j] = __float2bfloat16(W0[j]);
  for (int j = tid; j < 1024; j += 512) {
    int r = j >> 6, c = j & 63;
    x_s[r * 65 + c] = x[(b0 + r) * 64 + c];
  }
  if (tid < 256) {
    int r = tid >> 4, c = tid & 15;
    eps0s[r * 17 + c] = eps[((b0 + r) * NT) * 16 + c];
  }
  const float by_f = by[0];

  // persistent B-frags: wave w owns gate-cols i_own of r/z/n.
  bfrag Bh[3][4], Bi[3][2];
  #pragma unroll
  for (int g = 0; g < 3; g++) {
    int n = (g * 8 + w) * 16 + lmod;
    #pragma unroll
    for (int kc = 0; kc < 4; kc++) {
      int k = kc * 32 + ldiv * 8;
      const float* wh = Whh + n * 128 + k;
      float4 h0v = *reinterpret_cast<const float4*>(wh);
      float4 h1v = *reinterpret_cast<const float4*>(wh + 4);
      bfrag th = {f2bs(h0v.x), f2bs(h0v.y), f2bs(h0v.z), f2bs(h0v.w),
                  f2bs(h1v.x), f2bs(h1v.y), f2bs(h1v.z), f2bs(h1v.w)};
      Bh[g][kc] = th;
    }
    #pragma unroll
    for (int kc = 0; kc < 2; kc++) {
      bfrag ti;
      #pragma unroll
      for (int j = 0; j < 8; j++) {
        int dk = kc * 32 + ldiv * 8 + j;
        int col = dk < 48 ? dk : dk + 64;
        ti[j] = f2bs(Wih[n * 129 + col]);
      }
      Bi[g][kc] = ti;
    }
  }
  // logit B-tile for wave 7: col 0 = Wy, other cols 0
  bfrag Bl[4];
  if (w == 7) {
    #pragma unroll
    for (int kc = 0; kc < 4; kc++) {
      bfrag bt;
      #pragma unroll
      for (int j = 0; j < 8; j++)
        bt[j] = (lmod == 0) ? f2bs(Wy[kc * 32 + ldiv * 8 + j]) : (short)0;
      Bl[kc] = bt;
    }
  }
  __syncthreads();  // x_s, Wxb, tables ready

  // ph1: xenc = x@Wx.T + bx -> xe_s (f32) + xdyn bf16 (in h_bf[1])
  for (int j = tid; j < 1024; j += 512) {
    int r = j & 15, i = j >> 4;
    float acc = bx[i];
    #pragma unroll 8
    for (int k = 0; k < 64; k++) acc += x_s[r * 65 + k] * bf2f(Wxb[i * 64 + k]);
    xe_s[r * 65 + i] = acc;
    h_bf[1][r][i] = __float2bfloat16(acc);
  }
  __syncthreads();  // xe_s + xdyn ready; Wxb dead

  // ph2: h0 = tanh([xenc,eps0]@W0.T + b0) -> h0f (overwrites Wxb region)
  for (int j = tid; j < 2048; j += 512) {
    int r = j & 15, o = j >> 4;
    float acc = b0g[o];
    #pragma unroll 8
    for (int k = 0; k < 64; k++) acc += xe_s[r * 65 + k] * bf2f(W0b[o * 80 + k]);
    #pragma unroll
    for (int k = 0; k < 16; k++) acc += eps0s[r * 17 + k] * bf2f(W0b[o * 80 + 64 + k]);
    h0f[r * 128 + o] = tanh_f(acc);
  }

  // gxc = xenc @ Wih[:,48:112].T + per-gate biases folded into the seed
  ffrag gxc[3];
  {
    ffrag z = {0.f, 0.f, 0.f, 0.f};
    gxc[0] = z; gxc[1] = z; gxc[2] = z;
    #pragma unroll
    for (int kc = 0; kc < 2; kc++) {
      bfrag axd = *reinterpret_cast<const bfrag*>(&h_bf[1][lmod][kc * 32 + ldiv * 8]);
      #pragma unroll
      for (int g = 0; g < 3; g++) {
        int n = (g * 8 + w) * 16 + lmod;
        const float* wi = Wih + n * 129 + 48 + kc * 32 + ldiv * 8;
        bfrag bt;
        #pragma unroll
        for (int j = 0; j < 8; j++) bt[j] = f2bs(wi[j]);
        gxc[g] = __builtin_amdgcn_mfma_f32_16x16x32_bf16(axd, bt, gxc[g], 0, 0, 0);
      }
    }
    float brf = bsum_r[i_own], bzf = bsum_z[i_own], bn1 = bihn_s[i_own];
    #pragma unroll
    for (int q = 0; q < 4; q++) {
      gxc[0][q] += brf;
      gxc[1][q] += bzf;
      gxc[2][q] += bn1;
    }
  }
  __syncthreads();  // h0f complete; gxc done

  // h init: fp32 regs + bf16 mirror in h_bf[0]
  float h_reg[4];
  #pragma unroll
  for (int q = 0; q < 4; q++) {
    int row = ldiv * 4 + q;
    float hv = h0f[row * 128 + i_own];
    h_reg[q] = hv;
    h_bf[0][row][i_own] = __float2bfloat16(hv);
  }
  __syncthreads();  // h0f dead; uni becomes persistent

  // ids + chunk 0 of eps/y
  for (int j = tid; j < 4096; j += 512) {
    int r = j >> 8, t = j & 255;
    aid_s[r * 256 + t] = (unsigned short)a_ids[(b0 + r) * NT + t];
    tix_s[r * 256 + t] = (unsigned short)t_ids[(b0 + r) * NT + t];
  }
  {
    int r = tid >> 5, sub = tid & 31;
    const float* p = eps + ((b0 + r) * NT + 0) * 16 + sub * 8;
    float4 eA = *reinterpret_cast<const float4*>(p);
    float4 eB = *reinterpret_cast<const float4*>(p + 4);
    int toff = sub >> 1, c8 = (sub & 1) * 8;
    bfrag e = {f2bs(eA.x), f2bs(eA.y), f2bs(eA.z), f2bs(eA.w),
               f2bs(eB.x), f2bs(eB.y), f2bs(eB.z), f2bs(eB.w)};
    *reinterpret_cast<bfrag*>(&eps_ch[(toff * 16 + r) * 16 + c8]) = e;
    if (tid < 64) {
      int r2 = tid >> 2, s2 = tid & 3;
      float4 yv = *reinterpret_cast<const float4*>(y + (b0 + r2) * NT + s2 * 4);
      *reinterpret_cast<float4*>(&y_ch[r2 * 16 + s2 * 4]) = yv;
    }
  }
  if (tid < 16) prevy_s[0][tid] = 0.f;
  __syncthreads();

  // stage dyn input for t=0: 128 threads (waves 4-5) emb+eps
  const bool do_emb = (tid >= 256 && tid < 384);
  const int er8 = (tid - 256) >> 3, ch = (tid - 256) & 7;
  if (do_emb) {
    int j = tid - 256, r = j >> 3, c = j & 7;
    bfrag e;
    if (c < 4)      e = *reinterpret_cast<const bfrag*>(&Ea_s[aid_s[r * 256]][c * 8]);
    else if (c < 6) e = *reinterpret_cast<const bfrag*>(&Et_s[tix_s[r * 256]][(c - 4) * 8]);
    else            e = *reinterpret_cast<const bfrag*>(&eps_ch[(r) * 16 + (c - 6) * 8]);
    *reinterpret_cast<bfrag*>(&ind_s[0][r][c * 8]) = e;
  }
  // hoisted per-lane constants
  const float wpr = wprev_s[i_own], wpz = wprev_s[128 + i_own], wpn = wprev_s[256 + i_own];
  const float bn2 = bhhn_s[i_own];
  __syncthreads();

  // ================= MAIN LOOP =================
  for (int t = 0; t < NT; t++) {
    const int buf = t & 1, nbuf = buf ^ 1;

    // flush completed chunk (rare; waves 0-1)
    if ((t & 15) == 1 && t > 16 && tid < 128) {
      int fc = (t - 17) >> 4;
      int r = tid >> 3, k = tid & 7;
      int s = fc * 16 + 2 * k, slot = s & 31;
      float4 v;
      v.x = out_b[slot * 32 + r * 2];
      v.y = out_b[slot * 32 + r * 2 + 1];
      v.z = out_b[(slot + 1) * 32 + r * 2];
      v.w = out_b[(slot + 1) * 32 + r * 2 + 1];
      *reinterpret_cast<float4*>(out + ((b0 + r) * NT + s) * 2) = v;
    }

    // issue next-chunk global loads (rare)
    const bool ck = ((t & 15) == 0) && (t + 16 < NT);
    float4 eA, eB, yv;
    const int cr = tid >> 5, csub = tid & 31;
    if (ck) {
      const float* p = eps + ((b0 + cr) * NT + t + 16) * 16 + csub * 8;
      eA = *reinterpret_cast<const float4*>(p);
      eB = *reinterpret_cast<const float4*>(p + 4);
      if (tid < 64) {
        int r2 = tid >> 2, s2 = tid & 3;
        yv = *reinterpret_cast<const float4*>(y + (b0 + r2) * NT + t + 16 + s2 * 4);
      }
    }

    // stage step t+1 dyn input (waves 4-5)
    const int t1 = (t + 1 < NT) ? t + 1 : NT - 1;
    if (do_emb) {
      bfrag e;
      if (ch < 4)      e = *reinterpret_cast<const bfrag*>(&Ea_s[aid_s[er8 * 256 + t1]][ch * 8]);
      else if (ch < 6) e = *reinterpret_cast<const bfrag*>(&Et_s[tix_s[er8 * 256 + t1]][(ch - 4) * 8]);
      else             e = *reinterpret_cast<const bfrag*>(
                           &eps_ch[((((t1 >> 4) & 1) * 16 + (t1 & 15)) * 16 + er8) * 16 + (ch - 6) * 8]);
      *reinterpret_cast<bfrag*>(&ind_s[nbuf][er8][ch * 8]) = e;
    }
    // prevy for t+1 (wave 6)
    if (tid >= 384 && tid < 400) {
      int r = tid - 384;
      prevy_s[nbuf][r] = y_ch[((t >> 4) & 1) * 256 + r * 16 + (t & 15)];
    }

    // MFMA: merged accumulators
    ffrag ar = gxc[0], az = gxc[1], anx = gxc[2], anh, agl;
    #pragma unroll
    for (int q = 0; q < 4; q++) anh[q] = bn2;
    #pragma unroll
    for (int kc = 0; kc < 2; kc++) {
      bfrag ax = *reinterpret_cast<const bfrag*>(&ind_s[buf][lmod][kc * 32 + ldiv * 8]);
      ar  = __builtin_amdgcn_mfma_f32_16x16x32_bf16(ax, Bi[0][kc], ar, 0, 0, 0);
      az  = __builtin_amdgcn_mfma_f32_16x16x32_bf16(ax, Bi[1][kc], az, 0, 0, 0);
      anx = __builtin_amdgcn_mfma_f32_16x16x32_bf16(ax, Bi[2][kc], anx, 0, 0, 0);
    }
    if (w == 7) {
      #pragma unroll
      for (int q = 0; q < 4; q++) agl[q] = by_f;
    }
    #pragma unroll
    for (int kc = 0; kc < 4; kc++) {
      bfrag ah = *reinterpret_cast<const bfrag*>(&h_bf[buf][lmod][kc * 32 + ldiv * 8]);
      ar  = __builtin_amdgcn_mfma_f32_16x16x32_bf16(ah, Bh[0][kc], ar, 0, 0, 0);
      az  = __builtin_amdgcn_mfma_f32_16x16x32_bf16(ah, Bh[1][kc], az, 0, 0, 0);
      anh = __builtin_amdgcn_mfma_f32_16x16x32_bf16(ah, Bh[2][kc], anh, 0, 0, 0);
      if (w == 7)
        agl = __builtin_amdgcn_mfma_f32_16x16x32_bf16(ah, Bl[kc], agl, 0, 0, 0);
    }

    // wave 7: logit/prob for step t-1
    if (w == 7 && t > 0 && lmod == 0) {
      int slot = (t - 1) & 31;
      #pragma unroll
      for (int q = 0; q < 4; q++) {
        int row = ldiv * 4 + q;
        float lg = agl[q];
        out_b[slot * 32 + row * 2]     = lg;
        out_b[slot * 32 + row * 2 + 1] = sigm(lg);
      }
    }

    // S2: gates, h update
    #pragma unroll
    for (int q = 0; q < 4; q++) {
      int row = ldiv * 4 + q;
      float py = prevy_s[buf][row];
      float rv = sigm(__builtin_fmaf(py, wpr, ar[q]));
      float zv = sigm(__builtin_fmaf(py, wpz, az[q]));
      float nv = tanh_f(__builtin_fmaf(py, wpn, anx[q]) + rv * anh[q]);
      float hn = __builtin_fmaf(zv, h_reg[q] - nv, nv);
      h_reg[q] = hn;
      h_bf[nbuf][row][i_own] = __float2bfloat16(hn);
    }

    // next-chunk convert + LDS write (rare)
    if (ck) {
      int cb = ((t >> 4) + 1) & 1;
      int toff = csub >> 1, c8 = (csub & 1) * 8;
      bfrag e = {f2bs(eA.x), f2bs(eA.y), f2bs(eA.z), f2bs(eA.w),
                 f2bs(eB.x), f2bs(eB.y), f2bs(eB.z), f2bs(eB.w)};
      *reinterpret_cast<bfrag*>(&eps_ch[((cb * 16 + toff) * 16 + cr) * 16 + c8]) = e;
      if (tid < 64) {
        int r2 = tid >> 2, s2 = tid & 3;
        *reinterpret_cast<float4*>(&y_ch[cb * 256 + r2 * 16 + s2 * 4]) = yv;
      }
    }

    barrier_lgkm();  // the ONE barrier per step (LDS-only drain)
  }

  // ---- tail: logit for step 255 from h_bf[0] (= H_256), then flush ----
  if (w == 7) {
    ffrag agl;
    #pragma unroll
    for (int q = 0; q < 4; q++) agl[q] = by_f;
    #pragma unroll
    for (int kc = 0; kc < 4; kc++) {
      bfrag ah = *reinterpret_cast<const bfrag*>(&h_bf[0][lmod][kc * 32 + ldiv * 8]);
      agl = __builtin_amdgcn_mfma_f32_16x16x32_bf16(ah, Bl[kc], agl, 0, 0, 0);
    }
    if (lmod == 0) {
      #pragma unroll
      for (int q = 0; q < 4; q++) {
        int row = ldiv * 4 + q;
        float lg = agl[q];
        out_b[31 * 32 + row * 2]     = lg;
        out_b[31 * 32 + row * 2 + 1] = sigm(lg);
      }
    }
  }
  __syncthreads();
  if (tid < 128) {
    int r = tid >> 3, k = tid & 7;
    int s = 240 + 2 * k, slot = s & 31;
    float4 v;
    v.x = out_b[slot * 32 + r * 2];
    v.y = out_b[slot * 32 + r * 2 + 1];
    v.z = out_b[(slot + 1) * 32 + r * 2];
    v.w = out_b[(slot + 1) * 32 + r * 2 + 1];
    *reinterpret_cast<float4*>(out + ((b0 + r) * NT + s) * 2) = v;
  }
}

extern "C" void kernel_launch(void* const* d_in, const int* in_sizes, int n_in,
                              void* d_out, int out_size, void* d_ws, size_t ws_size,
                              hipStream_t stream) {
  const float* x   = (const float*)d_in[0];
  const int*   a   = (const int*)d_in[1];
  const int*   tt  = (const int*)d_in[2];
  const float* y   = (const float*)d_in[3];
  // d_in[4] = mask: forward output is mask-independent (m*v + (1-m)*v == v)
  const float* eps = (const float*)d_in[5];
  const float* Wx  = (const float*)d_in[6];
  const float* bx  = (const float*)d_in[7];
  const float* Ea  = (const float*)d_in[8];
  const float* Et  = (const float*)d_in[9];
  const float* Wih = (const float*)d_in[10];
  const float* Whh = (const float*)d_in[11];
  const float* bih = (const float*)d_in[12];
  const float* bhh = (const float*)d_in[13];
  const float* W0  = (const float*)d_in[14];
  const float* b0  = (const float*)d_in[15];
  const float* Wy  = (const float*)d_in[16];
  const float* by  = (const float*)d_in[17];
  float* out = (float*)d_out;

  gru_kernel<<<NB / 16, 512, 0, stream>>>(x, a, tt, y, eps, Wx, bx, Ea, Et,
                                          Wih, Whh, bih, bhh, W0, b0, Wy, by, out);
}